// Round 20
// baseline (335.257 us; speedup 1.0000x reference)
//
#include <hip/hip_runtime.h>

typedef unsigned short u16;
typedef __attribute__((ext_vector_type(8))) short bf16x8;
typedef __attribute__((ext_vector_type(4))) float f32x4;
typedef __attribute__((ext_vector_type(2))) unsigned int u32x2;
typedef __attribute__((ext_vector_type(4))) unsigned int u32x4;

#define GAS __attribute__((address_space(1)))
#define LAS __attribute__((address_space(3)))
#define MFMA __builtin_amdgcn_mfma_f32_16x16x32_bf16
#define BAR() __builtin_amdgcn_s_barrier()
#define WAITV(n) asm volatile("s_waitcnt vmcnt(" #n ")" ::: "memory")

__device__ __forceinline__ void gload16(const void* g, void* l) {
  __builtin_amdgcn_global_load_lds((GAS void*)g, (LAS void*)l, 16, 0, 0);
}
__device__ __forceinline__ u16 f2b(float x) {
  union { float f; unsigned u; } c; c.f = x;
  unsigned r = c.u + 0x7fffu + ((c.u >> 16) & 1u);
  return (u16)(r >> 16);
}
__device__ __forceinline__ float b2f(u16 h) {
  union { unsigned u; float f; } c; c.u = ((unsigned)h) << 16;
  return c.f;
}
__device__ __forceinline__ unsigned cvtpk(float lo, float hi) {
  unsigned r;
  asm("v_cvt_pk_bf16_f32 %0, %1, %2" : "=v"(r) : "v"(lo), "v"(hi));
  return r;
}

// ---------------- fused fp32 -> bf16 conversion (all 5 tensors, 1 launch) -------
__global__ __launch_bounds__(256) void cvt_all(
    const float* __restrict__ hs, const float* __restrict__ wq,
    const float* __restrict__ wk, const float* __restrict__ wv,
    const float* __restrict__ wo, u16* __restrict__ hsb,
    u16* __restrict__ wqkv, u16* __restrict__ wob) {
  int i = blockIdx.x * 256 + threadIdx.x;
  const float* src;
  u16* dst;
  int off;
  if (i < 1048576) {
    src = hs; dst = hsb; off = i;
  } else if (i < 2097152) {
    src = wq; dst = wqkv; off = i - 1048576;
  } else if (i < 2359296) {
    src = wk; dst = wqkv + 8388608; off = i - 2097152;
  } else if (i < 2621440) {
    src = wv; dst = wqkv + 10485760; off = i - 2359296;
  } else {
    src = wo; dst = wob; off = i - 2621440;
  }
  const float4* s4 = (const float4*)src;
  float4 a = s4[(size_t)off * 2], b = s4[(size_t)off * 2 + 1];
  u32x4 v;
  v[0] = (unsigned)f2b(a.x) | ((unsigned)f2b(a.y) << 16);
  v[1] = (unsigned)f2b(a.z) | ((unsigned)f2b(a.w) << 16);
  v[2] = (unsigned)f2b(b.x) | ((unsigned)f2b(b.y) << 16);
  v[3] = (unsigned)f2b(b.z) | ((unsigned)f2b(b.w) << 16);
  *(u32x4*)(dst + (size_t)off * 8) = v;
}

// ============ 256x256 8-phase GEMM (T2+T3+T4+T5) — proven template ============
// MODE 0 fused epilogue (Q/K: RMSNorm+RoPE; V: transposed), 2D XCD regions.
// MODE 1: split-K=2, plain-store fp32 partials to Dout/Daux (reduce sums).
template <int MODE>
__global__ __launch_bounds__(512, 2) void gemm256(
    const u16* __restrict__ A, const u16* __restrict__ B,
    u16* __restrict__ Dq, u16* __restrict__ Dk, u16* __restrict__ Dv,
    float* __restrict__ Dout, float* __restrict__ Daux,
    const float* __restrict__ cosT, const float* __restrict__ sinT,
    const float* __restrict__ qnw, const float* __restrict__ knw,
    int Kstride, int KLEN, int tilesN, int nwg) {
  __shared__ __attribute__((aligned(16))) u16 lds[2][2][2][128 * 64];
  __shared__ float ssl[4][256];
  const int tid = threadIdx.x;
  const int lane = tid & 63;
  const int w = tid >> 6;
  const int wr = w >> 2, wc = w & 3;
  const int r = lane & 15, g = lane >> 4;

  int bx, by, sk = 0;
  if (MODE == 0) {
    int xcd = blockIdx.x & 7;
    int idx = blockIdx.x >> 3;
    by = (xcd >> 2) * 8 + idx / 6;
    bx = (xcd & 3) * 6 + idx % 6;
  } else {
    int wg = blockIdx.x;
    const int cpx = nwg >> 3;
    wg = (wg & 7) * cpx + (wg >> 3);
    sk = wg >> 7; wg &= 127;
    bx = wg % tilesN; by = wg / tilesN;
  }
  const size_t m0 = (size_t)by * 256, n0 = (size_t)bx * 256;
  const size_t koff = (size_t)sk * KLEN;
  const int NT = KLEN >> 6;

  auto stage = [&](int dbuf, int op, int half, int c, int k0) {
    int slot = c * 512 + tid;
    int row = slot >> 3;
    int kg = (slot & 7) ^ (row & 7);
    const u16* src = (op == 0)
        ? A + (m0 + half * 128 + row) * (size_t)Kstride + koff + k0 + kg * 8
        : B + (n0 + half * 128 + row) * (size_t)Kstride + koff + k0 + kg * 8;
    gload16(src, (char*)&lds[dbuf][op][half][0] + c * 8192 + w * 1024);
  };
  auto ldA = [&](int cur, int mi, int kk) -> bf16x8 {
    int rowl = mi * 16 + r;
    return *(const bf16x8*)((const char*)&lds[cur][0][wr][0] + rowl * 128 +
                            (((kk << 2) + g) ^ (rowl & 7)) * 16);
  };
  auto ldB = [&](int cur, int ni, int kk) -> bf16x8 {
    int rowl = (wc & 1) * 64 + ni * 16 + r;
    return *(const bf16x8*)((const char*)&lds[cur][1][wc >> 1][0] + rowl * 128 +
                            (((kk << 2) + g) ^ (rowl & 7)) * 16);
  };

  f32x4 acc[8][4];
#pragma unroll
  for (int i = 0; i < 8; ++i)
#pragma unroll
    for (int j = 0; j < 4; ++j) acc[i][j] = (f32x4){0.f, 0.f, 0.f, 0.f};

  stage(0, 1, 0, 0, 0); stage(0, 1, 0, 1, 0);
  stage(0, 1, 1, 0, 0); stage(0, 1, 1, 1, 0);
  stage(0, 0, 0, 0, 0); stage(0, 0, 1, 0, 0);
  stage(0, 0, 0, 1, 0); stage(0, 0, 1, 1, 0);
  WAITV(2);
  BAR();

  bf16x8 bf_[4][2];

#define GPHASE(MI0, IS0, IS1, WAITCODE)                                    \
  {                                                                        \
    bf16x8 aA0 = ldA(cur, MI0, 0), aA1 = ldA(cur, MI0, 1);                 \
    bf16x8 aB0 = ldA(cur, MI0 + 1, 0), aB1 = ldA(cur, MI0 + 1, 1);         \
    IS0; IS1;                                                              \
    BAR();                                                                 \
    __builtin_amdgcn_s_setprio(1);                                         \
    _Pragma("unroll") for (int ni = 0; ni < 4; ++ni) {                     \
      acc[MI0][ni] = MFMA(aA0, bf_[ni][0], acc[MI0][ni], 0, 0, 0);         \
      acc[MI0][ni] = MFMA(aA1, bf_[ni][1], acc[MI0][ni], 0, 0, 0);         \
      acc[MI0 + 1][ni] = MFMA(aB0, bf_[ni][0], acc[MI0 + 1][ni], 0, 0, 0); \
      acc[MI0 + 1][ni] = MFMA(aB1, bf_[ni][1], acc[MI0 + 1][ni], 0, 0, 0); \
    }                                                                      \
    __builtin_amdgcn_s_setprio(0);                                         \
    WAITCODE;                                                              \
    BAR();                                                                 \
  }

  for (int t = 0; t < NT - 1; ++t) {
    const int cur = t & 1, nb = cur ^ 1;
    const int k1 = (t + 1) << 6;
#pragma unroll
    for (int ni = 0; ni < 4; ++ni) {
      bf_[ni][0] = ldB(cur, ni, 0);
      bf_[ni][1] = ldB(cur, ni, 1);
    }
    GPHASE(0, stage(nb, 1, 0, 0, k1), stage(nb, 1, 0, 1, k1), );
    GPHASE(2, stage(nb, 1, 1, 0, k1), stage(nb, 1, 1, 1, k1), WAITV(4));
    GPHASE(4, stage(nb, 0, 0, 0, k1), stage(nb, 0, 1, 0, k1), );
    GPHASE(6, stage(nb, 0, 0, 1, k1), stage(nb, 0, 1, 1, k1), WAITV(2));
  }
  {
    const int cur = (NT - 1) & 1;
#pragma unroll
    for (int ni = 0; ni < 4; ++ni) {
      bf_[ni][0] = ldB(cur, ni, 0);
      bf_[ni][1] = ldB(cur, ni, 1);
    }
    GPHASE(0, , , );
    GPHASE(2, , , WAITV(0));
    GPHASE(4, , , );
    GPHASE(6, , , );
  }
#undef GPHASE

  if (MODE == 1) {
    float* pbase = (sk == 0) ? Dout : Daux;
#pragma unroll
    for (int mi = 0; mi < 8; ++mi)
#pragma unroll
      for (int ni = 0; ni < 4; ++ni)
#pragma unroll
        for (int j = 0; j < 4; ++j) {
          int m = (int)m0 + wr * 128 + mi * 16 + g * 4 + j;
          int n = (int)n0 + wc * 64 + ni * 16 + r;
          pbase[(size_t)m * (size_t)(tilesN * 256) + n] = acc[mi][ni][j];
        }
    return;
  }

  // ================== MODE 0 fused epilogue ==================
  u16* lt = (u16*)&lds[0][0][0][0];

  if (bx < 20) {
    const bool isQ = (bx < 16);
    const float* nw = isQ ? qnw : knw;
    const float osc = isQ ? (0.08838834764831845f * 1.4426950408889634f) : 1.0f;

#pragma unroll
    for (int mi = 0; mi < 8; ++mi)
#pragma unroll
      for (int j = 0; j < 4; ++j) {
        float sq = 0.f;
#pragma unroll
        for (int ni = 0; ni < 4; ++ni) {
          float v = acc[mi][ni][j];
          sq += v * v;
        }
        sq += __shfl_xor(sq, 1);
        sq += __shfl_xor(sq, 2);
        sq += __shfl_xor(sq, 4);
        sq += __shfl_xor(sq, 8);
        ssl[wc][wr * 128 + mi * 16 + g * 4 + j] = sq;
      }
    BAR();

#pragma unroll
    for (int mi = 0; mi < 8; ++mi)
#pragma unroll
      for (int j = 0; j < 4; ++j) {
        int ml = wr * 128 + mi * 16 + g * 4 + j;
        float ss = ssl[wc & 2][ml] + ssl[(wc & 2) | 1][ml];
        float inv = rsqrtf(ss * (1.0f / 128.0f) + 1e-6f);
#pragma unroll
        for (int ni = 0; ni < 4; ++ni) {
          int d = (wc & 1) * 64 + ni * 16 + r;
          lt[ml * 256 + wc * 64 + ni * 16 + r] = f2b(acc[mi][ni][j] * inv * nw[d]);
        }
      }
    BAR();

#pragma unroll
    for (int t8 = 0; t8 < 8; ++t8) {
      int task = t8 * 512 + tid;
      int ml = task >> 4;
      int hd = (task >> 3) & 1;
      int gp = task & 7;
      int d0 = gp * 8;
      u32x4 xl = *(const u32x4*)(lt + ml * 256 + hd * 128 + d0);
      u32x4 xh = *(const u32x4*)(lt + ml * 256 + hd * 128 + 64 + d0);
      int m = (int)m0 + ml;
      int b = m >> 11, s = m & 2047;
      const float* cb = cosT + s * 128 + d0;
      const float* sb = sinT + s * 128 + d0;
      float4 c0a = *(const float4*)(cb), c0b = *(const float4*)(cb + 4);
      float4 s0a = *(const float4*)(sb), s0b = *(const float4*)(sb + 4);
      float4 c1a = *(const float4*)(cb + 64), c1b = *(const float4*)(cb + 68);
      float4 s1a = *(const float4*)(sb + 64), s1b = *(const float4*)(sb + 68);
      float x0[8], x1[8];
#pragma unroll
      for (int e = 0; e < 4; ++e) {
        x0[2 * e] = b2f((u16)(xl[e] & 0xffffu));
        x0[2 * e + 1] = b2f((u16)(xl[e] >> 16));
        x1[2 * e] = b2f((u16)(xh[e] & 0xffffu));
        x1[2 * e + 1] = b2f((u16)(xh[e] >> 16));
      }
      float c0[8] = {c0a.x, c0a.y, c0a.z, c0a.w, c0b.x, c0b.y, c0b.z, c0b.w};
      float s0[8] = {s0a.x, s0a.y, s0a.z, s0a.w, s0b.x, s0b.y, s0b.z, s0b.w};
      float c1[8] = {c1a.x, c1a.y, c1a.z, c1a.w, c1b.x, c1b.y, c1b.z, c1b.w};
      float s1[8] = {s1a.x, s1a.y, s1a.z, s1a.w, s1b.x, s1b.y, s1b.z, s1b.w};
      u32x4 y0, y1;
#pragma unroll
      for (int e = 0; e < 4; ++e) {
        float a0 = (x0[2 * e] * c0[2 * e] - x1[2 * e] * s0[2 * e]) * osc;
        float a1 = (x0[2 * e + 1] * c0[2 * e + 1] - x1[2 * e + 1] * s0[2 * e + 1]) * osc;
        y0[e] = cvtpk(a0, a1);
        float b0 = (x1[2 * e] * c1[2 * e] + x0[2 * e] * s1[2 * e]) * osc;
        float b1 = (x1[2 * e + 1] * c1[2 * e + 1] + x0[2 * e + 1] * s1[2 * e + 1]) * osc;
        y1[e] = cvtpk(b0, b1);
      }
      if (isQ) {
        int hq = 2 * bx + hd;
        u16* dst = Dq + (((size_t)b * 32 + hq) * 2048 + s) * 128 + d0;
        *(u32x4*)dst = y0;
        *(u32x4*)(dst + 64) = y1;
      } else {
        int hk = 2 * (bx - 16) + hd;
        u16* dst = Dk + (((size_t)b * 8 + hk) * 2048 + s) * 128 + d0;
        *(u32x4*)dst = y0;
        *(u32x4*)(dst + 64) = y1;
      }
    }
  } else {
#pragma unroll
    for (int mi = 0; mi < 8; ++mi)
#pragma unroll
      for (int ni = 0; ni < 4; ++ni)
#pragma unroll
        for (int j = 0; j < 4; ++j) {
          int ml = wr * 128 + mi * 16 + g * 4 + j;
          int nl = wc * 64 + ni * 16 + r;
          int gm = ml >> 3;
          lt[nl * 256 + (((gm ^ (nl & 7)) << 3) | (ml & 7))] = f2b(acc[mi][ni][j]);
        }
    BAR();
#pragma unroll
    for (int t16 = 0; t16 < 16; ++t16) {
      int task = t16 * 512 + tid;
      int nl = task >> 5;
      int mg = task & 31;
      u32x4 v = *(const u32x4*)(lt + nl * 256 + ((mg ^ (nl & 7)) << 3));
      int hv = 2 * (bx - 20) + (nl >> 7);
      int d = nl & 127;
      int m = (int)m0 + mg * 8;
      int b = m >> 11, s = m & 2047;
      *(u32x4*)(Dv + (((size_t)b * 8 + hv) * 128 + d) * 2048 + s) = v;
    }
  }
}

// ---------------- split-K reduce: out = P0 + P1 (float4, 1:1 map) ----------------
__global__ __launch_bounds__(256) void reduce_add(const float* __restrict__ P0,
                                                  const float* __restrict__ P1,
                                                  float* __restrict__ out, int n4) {
  int i = blockIdx.x * 256 + threadIdx.x;
  if (i >= n4) return;
  float4 a = ((const float4*)P0)[i];
  float4 b = ((const float4*)P1)[i];
  a.x += b.x; a.y += b.y; a.z += b.z; a.w += b.w;
  ((float4*)out)[i] = a;
}

// ---------------- causal GQA flash attention (8 waves, QBLK=256, K/V dbuf) ------
// Block p pairs Q-tiles {7-p, p} (uniform 36 KV-units). 8 waves x 32 q-rows
// (2 frags). Grid 4x32x2 = 256 = exactly 1 block/CU; staged K/V tile shared
// by 8 waves (staging bytes/barriers per unit of work HALVED vs 4-wave).
// NO-MAX softmax (bounded S), P = exp2(S) directly, ones-MFMA row-sums.
__global__ __launch_bounds__(512, 2) void attn_fwd(const u16* __restrict__ Q,
                                                   const u16* __restrict__ Kg,
                                                   const u16* __restrict__ Vg,
                                                   u16* __restrict__ AO) {
  __shared__ __attribute__((aligned(16))) u16 Ks[2][64 * 128];
  __shared__ __attribute__((aligned(16))) u16 Vt[2][128 * 64];
  __shared__ __attribute__((aligned(16))) u16 Plds[8][32 * 64];
  const int tid = threadIdx.x;
  const int lane = tid & 63;
  const int w = tid >> 6;  // 0..7
  const int r = lane & 15, g = lane >> 4;
  const int p = blockIdx.x, h = blockIdx.y, b = blockIdx.z;
  const int hkv = h >> 2;

  const u16* Kp = Kg + (((size_t)b * 8 + hkv) * 2048) * 128;
  const u16* Vp = Vg + (((size_t)b * 8 + hkv) * 128) * 2048;

  const short one_bf = (short)0x3F80;
  const bf16x8 vones = {one_bf, one_bf, one_bf, one_bf, one_bf, one_bf, one_bf, one_bf};

#pragma unroll 1
  for (int phase = 0; phase < 2; ++phase) {
    const int qt = phase == 0 ? (7 - p) : p;
    const u16* Qp = Q + (((size_t)b * 32 + h) * 2048 + qt * 256 + w * 32) * 128;

    bf16x8 qf[2][4];
#pragma unroll
    for (int f = 0; f < 2; ++f)
#pragma unroll
      for (int kk = 0; kk < 4; ++kk)
        qf[f][kk] = *(const bf16x8*)(Qp + (f * 16 + r) * 128 + kk * 32 + g * 8);

    f32x4 off[2][8];
#pragma unroll
    for (int f = 0; f < 2; ++f)
#pragma unroll
      for (int i = 0; i < 8; ++i) off[f][i] = (f32x4){0.f, 0.f, 0.f, 0.f};
    f32x4 lr4[2] = {(f32x4){0.f, 0.f, 0.f, 0.f}, (f32x4){0.f, 0.f, 0.f, 0.f}};
    const int qg0 = qt * 256 + w * 32 + r;
    const int qg1 = qg0 + 16;

    // staging: 512 threads, 2 chunks each for K (1024 slots) and V (1024 slots)
    const u16* kst[2];
    const u16* vst[2];
#pragma unroll
    for (int c = 0; c < 2; ++c) {
      int t = c * 512 + tid;
      kst[c] = Kp + (size_t)(t >> 4) * 128 + (size_t)(((t & 15) ^ ((t >> 4) & 7)) * 8);
      int d = t >> 3;
      vst[c] = Vp + (size_t)d * 2048 + (size_t)(((t & 7) ^ ((d >> 1) & 7)) * 8);
    }
    auto stageKV = [&](int buf) {
#pragma unroll
      for (int c = 0; c < 2; ++c) {
        gload16(kst[c], (char*)&Ks[buf][0] + c * 8192 + w * 1024);
        kst[c] += 64 * 128;
      }
#pragma unroll
      for (int c = 0; c < 2; ++c) {
        gload16(vst[c], (char*)&Vt[buf][0] + c * 8192 + w * 1024);
        vst[c] += 64;
      }
    };

    const int nu = 4 * qt + 4;

    stageKV(0);
    WAITV(0);
    BAR();

    for (int kt = 0; kt < nu; ++kt) {
      const int cur = kt & 1;
      if (kt + 1 < nu) stageKV(cur ^ 1);

      const char* KsC = (const char*)&Ks[cur][0];
      const char* VtC = (const char*)&Vt[cur][0];

      f32x4 sc0[4], sc1[4];
#pragma unroll
      for (int ni = 0; ni < 4; ++ni) {
        f32x4 a0 = (f32x4){0.f, 0.f, 0.f, 0.f};
        f32x4 a1 = (f32x4){0.f, 0.f, 0.f, 0.f};
        int ro = ni * 16 + r;
#pragma unroll
        for (int kk = 0; kk < 4; ++kk) {
          int slot = (ro * 16 + kk * 4 + g) ^ (ro & 7);
          bf16x8 kf = *(const bf16x8*)(KsC + slot * 16);
          a0 = MFMA(kf, qf[0][kk], a0, 0, 0, 0);
          a1 = MFMA(kf, qf[1][kk], a1, 0, 0, 0);
        }
        sc0[ni] = a0;
        sc1[ni] = a1;
      }

      if (kt >= 4 * qt) {  // diagonal block region (last 4 units)
#pragma unroll
        for (int ni = 0; ni < 4; ++ni)
#pragma unroll
          for (int j = 0; j < 4; ++j) {
            int kvg = kt * 64 + ni * 16 + g * 4 + j;
            sc0[ni][j] = (kvg > qg0) ? -1e30f : sc0[ni][j];
            sc1[ni][j] = (kvg > qg1) ? -1e30f : sc1[ni][j];
          }
      }

      {
        char* pw = (char*)&Plds[w][0];
        int sw = (r & 7) << 4;
#pragma unroll
        for (int ni = 0; ni < 4; ++ni) {
          u32x2 pr0, pr1;
          pr0[0] = cvtpk(exp2f(sc0[ni][0]), exp2f(sc0[ni][1]));
          pr0[1] = cvtpk(exp2f(sc0[ni][2]), exp2f(sc0[ni][3]));
          pr1[0] = cvtpk(exp2f(sc1[ni][0]), exp2f(sc1[ni][1]));
          pr1[1] = cvtpk(exp2f(sc1[ni][2]), exp2f(sc1[ni][3]));
          *(u32x2*)(pw + ((r * 128 + ni * 32 + g * 8) ^ sw)) = pr0;
          *(u32x2*)(pw + (((16 + r) * 128 + ni * 32 + g * 8) ^ sw)) = pr1;
        }
      }
      bf16x8 pa[2][2];
      {
        const char* pw = (const char*)&Plds[w][0];
        int sw = (r & 7) << 4;
#pragma unroll
        for (int kk = 0; kk < 2; ++kk) {
          pa[0][kk] = *(const bf16x8*)(pw + ((r * 128 + kk * 64 + g * 16) ^ sw));
          pa[1][kk] = *(const bf16x8*)(pw + (((16 + r) * 128 + kk * 64 + g * 16) ^ sw));
        }
      }

      lr4[0] = MFMA(pa[0][0], vones, lr4[0], 0, 0, 0);
      lr4[0] = MFMA(pa[0][1], vones, lr4[0], 0, 0, 0);
      lr4[1] = MFMA(pa[1][0], vones, lr4[1], 0, 0, 0);
      lr4[1] = MFMA(pa[1][1], vones, lr4[1], 0, 0, 0);

#pragma unroll
      for (int dd = 0; dd < 8; ++dd) {
        int d = dd * 16 + r;
#pragma unroll
        for (int kk = 0; kk < 2; ++kk) {
          int ph = (kk * 4 + g) ^ ((r >> 1) & 7);
          bf16x8 vf = *(const bf16x8*)(VtC + (size_t)d * 128 + ph * 16);
          off[0][dd] = MFMA(pa[0][kk], vf, off[0][dd], 0, 0, 0);
          off[1][dd] = MFMA(pa[1][kk], vf, off[1][dd], 0, 0, 0);
        }
      }

      WAITV(0);
      BAR();
    }

#pragma unroll
    for (int f = 0; f < 2; ++f) {
      f32x4 il4;
#pragma unroll
      for (int j = 0; j < 4; ++j) il4[j] = 1.0f / lr4[f][j];
      const size_t ob = (size_t)b * 2048 + qt * 256 + w * 32 + f * 16 + g * 4;
#pragma unroll
      for (int dd = 0; dd < 8; ++dd) {
        AO[(ob + 0) * 4096 + h * 128 + dd * 16 + r] = f2b(off[f][dd][0] * il4[0]);
        AO[(ob + 1) * 4096 + h * 128 + dd * 16 + r] = f2b(off[f][dd][1] * il4[1]);
        AO[(ob + 2) * 4096 + h * 128 + dd * 16 + r] = f2b(off[f][dd][2] * il4[2]);
        AO[(ob + 3) * 4096 + h * 128 + dd * 16 + r] = f2b(off[f][dd][3] * il4[3]);
      }
    }
  }
}

// ---------------- launch ----------------
extern "C" void kernel_launch(void* const* d_in, const int* in_sizes, int n_in,
                              void* d_out, int out_size, void* d_ws, size_t ws_size,
                              hipStream_t stream) {
  (void)in_sizes; (void)n_in; (void)out_size; (void)ws_size;
  const float* hs = (const float*)d_in[0];
  const float* cosT = (const float*)d_in[1];
  const float* sinT = (const float*)d_in[2];
  const float* wq = (const float*)d_in[3];
  const float* wk = (const float*)d_in[4];
  const float* wv = (const float*)d_in[5];
  const float* wo = (const float*)d_in[6];
  const float* qnw = (const float*)d_in[7];
  const float* knw = (const float*)d_in[8];
  float* out = (float*)d_out;

  char* ws = (char*)d_ws;
  u16* hsb  = (u16*)(ws);                   // [4096,2048]      16 MB
  u16* wqkv = (u16*)(ws + 16777216);        // [6144,2048]      24 MB
  u16* wob  = (u16*)(ws + 41943040);        // [2048,4096]      16 MB
  u16* Qb   = (u16*)(ws + 58720256);        // [2,32,2048,128]  32 MB
  u16* Kb   = (u16*)(ws + 92274688);        // [2,8,2048,128]    8 MB
  u16* VTb  = (u16*)(ws + 100663296);       // [2,8,128,2048]    8 MB (transposed)
  u16* AO   = (u16*)(ws + 109051904);       // [4096,4096]      32 MB
  float* P0 = (float*)(ws + 58720256);      // 32 MB, aliases Qb (dead after attn)
  float* P1 = (float*)(ws);                 // 32 MB, aliases hsb+wqkv

  // 1) fp32 -> bf16 (all tensors, one launch)
  cvt_all<<<14336, 256, 0, stream>>>(hs, wq, wk, wv, wo, hsb, wqkv, wob);

  // 2) fused QKV projection + RMSNorm + RoPE + V-transpose (2D XCD regions)
  gemm256<0><<<384, 512, 0, stream>>>(hsb, wqkv, Qb, Kb, VTb, nullptr, nullptr,
                                      cosT, sinT, qnw, knw, 2048, 2048, 24, 384);

  // 3) causal GQA flash attention (8 waves, QBLK=256, paired {7-p,p}) -> AO
  attn_fwd<<<dim3(4, 32, 2), 512, 0, stream>>>(Qb, Kb, VTb, AO);

  // 4) output projection: split-K=2 plain-store partials, then reduce
  gemm256<1><<<256, 512, 0, stream>>>(AO, wob, nullptr, nullptr, nullptr, P0, P1,
                                      nullptr, nullptr, nullptr, nullptr,
                                      4096, 2048, 8, 256);
  reduce_add<<<8192, 256, 0, stream>>>(P0, P1, out, 2097152);
}

// Round 21
// 324.210 us; speedup vs baseline: 1.0341x; 1.0341x over previous
//
#include <hip/hip_runtime.h>

typedef unsigned short u16;
typedef __attribute__((ext_vector_type(8))) short bf16x8;
typedef __attribute__((ext_vector_type(4))) float f32x4;
typedef __attribute__((ext_vector_type(2))) unsigned int u32x2;
typedef __attribute__((ext_vector_type(4))) unsigned int u32x4;

#define GAS __attribute__((address_space(1)))
#define LAS __attribute__((address_space(3)))
#define MFMA __builtin_amdgcn_mfma_f32_16x16x32_bf16
#define BAR() __builtin_amdgcn_s_barrier()
#define WAITV(n) asm volatile("s_waitcnt vmcnt(" #n ")" ::: "memory")

__device__ __forceinline__ void gload16(const void* g, void* l) {
  __builtin_amdgcn_global_load_lds((GAS void*)g, (LAS void*)l, 16, 0, 0);
}
__device__ __forceinline__ u16 f2b(float x) {
  union { float f; unsigned u; } c; c.f = x;
  unsigned r = c.u + 0x7fffu + ((c.u >> 16) & 1u);
  return (u16)(r >> 16);
}
__device__ __forceinline__ float b2f(u16 h) {
  union { unsigned u; float f; } c; c.u = ((unsigned)h) << 16;
  return c.f;
}
__device__ __forceinline__ unsigned cvtpk(float lo, float hi) {
  unsigned r;
  asm("v_cvt_pk_bf16_f32 %0, %1, %2" : "=v"(r) : "v"(lo), "v"(hi));
  return r;
}

// ---------------- fused fp32 -> bf16 conversion (all 5 tensors, 1 launch) -------
__global__ __launch_bounds__(256) void cvt_all(
    const float* __restrict__ hs, const float* __restrict__ wq,
    const float* __restrict__ wk, const float* __restrict__ wv,
    const float* __restrict__ wo, u16* __restrict__ hsb,
    u16* __restrict__ wqkv, u16* __restrict__ wob) {
  int i = blockIdx.x * 256 + threadIdx.x;
  const float* src;
  u16* dst;
  int off;
  if (i < 1048576) {
    src = hs; dst = hsb; off = i;
  } else if (i < 2097152) {
    src = wq; dst = wqkv; off = i - 1048576;
  } else if (i < 2359296) {
    src = wk; dst = wqkv + 8388608; off = i - 2097152;
  } else if (i < 2621440) {
    src = wv; dst = wqkv + 10485760; off = i - 2359296;
  } else {
    src = wo; dst = wob; off = i - 2621440;
  }
  const float4* s4 = (const float4*)src;
  float4 a = s4[(size_t)off * 2], b = s4[(size_t)off * 2 + 1];
  u32x4 v;
  v[0] = (unsigned)f2b(a.x) | ((unsigned)f2b(a.y) << 16);
  v[1] = (unsigned)f2b(a.z) | ((unsigned)f2b(a.w) << 16);
  v[2] = (unsigned)f2b(b.x) | ((unsigned)f2b(b.y) << 16);
  v[3] = (unsigned)f2b(b.z) | ((unsigned)f2b(b.w) << 16);
  *(u32x4*)(dst + (size_t)off * 8) = v;
}

// ============ 256x256 8-phase GEMM (T2+T3+T4+T5) — proven template ============
// MODE 0 fused epilogue (Q/K: RMSNorm+RoPE; V: transposed), 2D XCD regions.
// MODE 1: split-K=2, plain-store fp32 partials to Dout/Daux (reduce sums).
template <int MODE>
__global__ __launch_bounds__(512, 2) void gemm256(
    const u16* __restrict__ A, const u16* __restrict__ B,
    u16* __restrict__ Dq, u16* __restrict__ Dk, u16* __restrict__ Dv,
    float* __restrict__ Dout, float* __restrict__ Daux,
    const float* __restrict__ cosT, const float* __restrict__ sinT,
    const float* __restrict__ qnw, const float* __restrict__ knw,
    int Kstride, int KLEN, int tilesN, int nwg) {
  __shared__ __attribute__((aligned(16))) u16 lds[2][2][2][128 * 64];
  __shared__ float ssl[4][256];
  const int tid = threadIdx.x;
  const int lane = tid & 63;
  const int w = tid >> 6;
  const int wr = w >> 2, wc = w & 3;
  const int r = lane & 15, g = lane >> 4;

  int bx, by, sk = 0;
  if (MODE == 0) {
    // 2D XCD-region swizzle: grid 384 = 8 XCD x 48; region 8 by x 6 bx
    int xcd = blockIdx.x & 7;
    int idx = blockIdx.x >> 3;
    by = (xcd >> 2) * 8 + idx / 6;
    bx = (xcd & 3) * 6 + idx % 6;
  } else {
    int wg = blockIdx.x;
    const int cpx = nwg >> 3;
    wg = (wg & 7) * cpx + (wg >> 3);
    sk = wg >> 7; wg &= 127;
    bx = wg % tilesN; by = wg / tilesN;
  }
  const size_t m0 = (size_t)by * 256, n0 = (size_t)bx * 256;
  const size_t koff = (size_t)sk * KLEN;
  const int NT = KLEN >> 6;

  auto stage = [&](int dbuf, int op, int half, int c, int k0) {
    int slot = c * 512 + tid;
    int row = slot >> 3;
    int kg = (slot & 7) ^ (row & 7);
    const u16* src = (op == 0)
        ? A + (m0 + half * 128 + row) * (size_t)Kstride + koff + k0 + kg * 8
        : B + (n0 + half * 128 + row) * (size_t)Kstride + koff + k0 + kg * 8;
    gload16(src, (char*)&lds[dbuf][op][half][0] + c * 8192 + w * 1024);
  };
  auto ldA = [&](int cur, int mi, int kk) -> bf16x8 {
    int rowl = mi * 16 + r;
    return *(const bf16x8*)((const char*)&lds[cur][0][wr][0] + rowl * 128 +
                            (((kk << 2) + g) ^ (rowl & 7)) * 16);
  };
  auto ldB = [&](int cur, int ni, int kk) -> bf16x8 {
    int rowl = (wc & 1) * 64 + ni * 16 + r;
    return *(const bf16x8*)((const char*)&lds[cur][1][wc >> 1][0] + rowl * 128 +
                            (((kk << 2) + g) ^ (rowl & 7)) * 16);
  };

  f32x4 acc[8][4];
#pragma unroll
  for (int i = 0; i < 8; ++i)
#pragma unroll
    for (int j = 0; j < 4; ++j) acc[i][j] = (f32x4){0.f, 0.f, 0.f, 0.f};

  stage(0, 1, 0, 0, 0); stage(0, 1, 0, 1, 0);
  stage(0, 1, 1, 0, 0); stage(0, 1, 1, 1, 0);
  stage(0, 0, 0, 0, 0); stage(0, 0, 1, 0, 0);
  stage(0, 0, 0, 1, 0); stage(0, 0, 1, 1, 0);
  WAITV(2);
  BAR();

  bf16x8 bf_[4][2];

#define GPHASE(MI0, IS0, IS1, WAITCODE)                                    \
  {                                                                        \
    bf16x8 aA0 = ldA(cur, MI0, 0), aA1 = ldA(cur, MI0, 1);                 \
    bf16x8 aB0 = ldA(cur, MI0 + 1, 0), aB1 = ldA(cur, MI0 + 1, 1);         \
    IS0; IS1;                                                              \
    BAR();                                                                 \
    __builtin_amdgcn_s_setprio(1);                                         \
    _Pragma("unroll") for (int ni = 0; ni < 4; ++ni) {                     \
      acc[MI0][ni] = MFMA(aA0, bf_[ni][0], acc[MI0][ni], 0, 0, 0);         \
      acc[MI0][ni] = MFMA(aA1, bf_[ni][1], acc[MI0][ni], 0, 0, 0);         \
      acc[MI0 + 1][ni] = MFMA(aB0, bf_[ni][0], acc[MI0 + 1][ni], 0, 0, 0); \
      acc[MI0 + 1][ni] = MFMA(aB1, bf_[ni][1], acc[MI0 + 1][ni], 0, 0, 0); \
    }                                                                      \
    __builtin_amdgcn_s_setprio(0);                                         \
    WAITCODE;                                                              \
    BAR();                                                                 \
  }

  for (int t = 0; t < NT - 1; ++t) {
    const int cur = t & 1, nb = cur ^ 1;
    const int k1 = (t + 1) << 6;
#pragma unroll
    for (int ni = 0; ni < 4; ++ni) {
      bf_[ni][0] = ldB(cur, ni, 0);
      bf_[ni][1] = ldB(cur, ni, 1);
    }
    GPHASE(0, stage(nb, 1, 0, 0, k1), stage(nb, 1, 0, 1, k1), );
    GPHASE(2, stage(nb, 1, 1, 0, k1), stage(nb, 1, 1, 1, k1), WAITV(4));
    GPHASE(4, stage(nb, 0, 0, 0, k1), stage(nb, 0, 1, 0, k1), );
    GPHASE(6, stage(nb, 0, 0, 1, k1), stage(nb, 0, 1, 1, k1), WAITV(2));
  }
  {
    const int cur = (NT - 1) & 1;
#pragma unroll
    for (int ni = 0; ni < 4; ++ni) {
      bf_[ni][0] = ldB(cur, ni, 0);
      bf_[ni][1] = ldB(cur, ni, 1);
    }
    GPHASE(0, , , );
    GPHASE(2, , , WAITV(0));
    GPHASE(4, , , );
    GPHASE(6, , , );
  }
#undef GPHASE

  if (MODE == 1) {
    float* pbase = (sk == 0) ? Dout : Daux;
#pragma unroll
    for (int mi = 0; mi < 8; ++mi)
#pragma unroll
      for (int ni = 0; ni < 4; ++ni)
#pragma unroll
        for (int j = 0; j < 4; ++j) {
          int m = (int)m0 + wr * 128 + mi * 16 + g * 4 + j;
          int n = (int)n0 + wc * 64 + ni * 16 + r;
          pbase[(size_t)m * (size_t)(tilesN * 256) + n] = acc[mi][ni][j];
        }
    return;
  }

  // ================== MODE 0 fused epilogue ==================
  u16* lt = (u16*)&lds[0][0][0][0];

  if (bx < 20) {
    const bool isQ = (bx < 16);
    const float* nw = isQ ? qnw : knw;
    const float osc = isQ ? (0.08838834764831845f * 1.4426950408889634f) : 1.0f;

#pragma unroll
    for (int mi = 0; mi < 8; ++mi)
#pragma unroll
      for (int j = 0; j < 4; ++j) {
        float sq = 0.f;
#pragma unroll
        for (int ni = 0; ni < 4; ++ni) {
          float v = acc[mi][ni][j];
          sq += v * v;
        }
        sq += __shfl_xor(sq, 1);
        sq += __shfl_xor(sq, 2);
        sq += __shfl_xor(sq, 4);
        sq += __shfl_xor(sq, 8);
        ssl[wc][wr * 128 + mi * 16 + g * 4 + j] = sq;
      }
    BAR();

#pragma unroll
    for (int mi = 0; mi < 8; ++mi)
#pragma unroll
      for (int j = 0; j < 4; ++j) {
        int ml = wr * 128 + mi * 16 + g * 4 + j;
        float ss = ssl[wc & 2][ml] + ssl[(wc & 2) | 1][ml];
        float inv = rsqrtf(ss * (1.0f / 128.0f) + 1e-6f);
#pragma unroll
        for (int ni = 0; ni < 4; ++ni) {
          int d = (wc & 1) * 64 + ni * 16 + r;
          lt[ml * 256 + wc * 64 + ni * 16 + r] = f2b(acc[mi][ni][j] * inv * nw[d]);
        }
      }
    BAR();

#pragma unroll
    for (int t8 = 0; t8 < 8; ++t8) {
      int task = t8 * 512 + tid;
      int ml = task >> 4;
      int hd = (task >> 3) & 1;
      int gp = task & 7;
      int d0 = gp * 8;
      u32x4 xl = *(const u32x4*)(lt + ml * 256 + hd * 128 + d0);
      u32x4 xh = *(const u32x4*)(lt + ml * 256 + hd * 128 + 64 + d0);
      int m = (int)m0 + ml;
      int b = m >> 11, s = m & 2047;
      const float* cb = cosT + s * 128 + d0;
      const float* sb = sinT + s * 128 + d0;
      float4 c0a = *(const float4*)(cb), c0b = *(const float4*)(cb + 4);
      float4 s0a = *(const float4*)(sb), s0b = *(const float4*)(sb + 4);
      float4 c1a = *(const float4*)(cb + 64), c1b = *(const float4*)(cb + 68);
      float4 s1a = *(const float4*)(sb + 64), s1b = *(const float4*)(sb + 68);
      float x0[8], x1[8];
#pragma unroll
      for (int e = 0; e < 4; ++e) {
        x0[2 * e] = b2f((u16)(xl[e] & 0xffffu));
        x0[2 * e + 1] = b2f((u16)(xl[e] >> 16));
        x1[2 * e] = b2f((u16)(xh[e] & 0xffffu));
        x1[2 * e + 1] = b2f((u16)(xh[e] >> 16));
      }
      float c0[8] = {c0a.x, c0a.y, c0a.z, c0a.w, c0b.x, c0b.y, c0b.z, c0b.w};
      float s0[8] = {s0a.x, s0a.y, s0a.z, s0a.w, s0b.x, s0b.y, s0b.z, s0b.w};
      float c1[8] = {c1a.x, c1a.y, c1a.z, c1a.w, c1b.x, c1b.y, c1b.z, c1b.w};
      float s1[8] = {s1a.x, s1a.y, s1a.z, s1a.w, s1b.x, s1b.y, s1b.z, s1b.w};
      u32x4 y0, y1;
#pragma unroll
      for (int e = 0; e < 4; ++e) {
        float a0 = (x0[2 * e] * c0[2 * e] - x1[2 * e] * s0[2 * e]) * osc;
        float a1 = (x0[2 * e + 1] * c0[2 * e + 1] - x1[2 * e + 1] * s0[2 * e + 1]) * osc;
        y0[e] = cvtpk(a0, a1);
        float b0 = (x1[2 * e] * c1[2 * e] + x0[2 * e] * s1[2 * e]) * osc;
        float b1 = (x1[2 * e + 1] * c1[2 * e + 1] + x0[2 * e + 1] * s1[2 * e + 1]) * osc;
        y1[e] = cvtpk(b0, b1);
      }
      if (isQ) {
        int hq = 2 * bx + hd;
        u16* dst = Dq + (((size_t)b * 32 + hq) * 2048 + s) * 128 + d0;
        *(u32x4*)dst = y0;
        *(u32x4*)(dst + 64) = y1;
      } else {
        int hk = 2 * (bx - 16) + hd;
        u16* dst = Dk + (((size_t)b * 8 + hk) * 2048 + s) * 128 + d0;
        *(u32x4*)dst = y0;
        *(u32x4*)(dst + 64) = y1;
      }
    }
  } else {
#pragma unroll
    for (int mi = 0; mi < 8; ++mi)
#pragma unroll
      for (int ni = 0; ni < 4; ++ni)
#pragma unroll
        for (int j = 0; j < 4; ++j) {
          int ml = wr * 128 + mi * 16 + g * 4 + j;
          int nl = wc * 64 + ni * 16 + r;
          int gm = ml >> 3;
          lt[nl * 256 + (((gm ^ (nl & 7)) << 3) | (ml & 7))] = f2b(acc[mi][ni][j]);
        }
    BAR();
#pragma unroll
    for (int t16 = 0; t16 < 16; ++t16) {
      int task = t16 * 512 + tid;
      int nl = task >> 5;
      int mg = task & 31;
      u32x4 v = *(const u32x4*)(lt + nl * 256 + ((mg ^ (nl & 7)) << 3));
      int hv = 2 * (bx - 20) + (nl >> 7);
      int d = nl & 127;
      int m = (int)m0 + mg * 8;
      int b = m >> 11, s = m & 2047;
      *(u32x4*)(Dv + (((size_t)b * 8 + hv) * 128 + d) * 2048 + s) = v;
    }
  }
}

// ---------------- split-K reduce: out = P0 + P1 (float4, 1:1 map) ----------------
__global__ __launch_bounds__(256) void reduce_add(const float* __restrict__ P0,
                                                  const float* __restrict__ P1,
                                                  float* __restrict__ out, int n4) {
  int i = blockIdx.x * 256 + threadIdx.x;
  if (i >= n4) return;
  float4 a = ((const float4*)P0)[i];
  float4 b = ((const float4*)P1)[i];
  a.x += b.x; a.y += b.y; a.z += b.z; a.w += b.w;
  ((float4*)out)[i] = a;
}

// ---------------- causal GQA flash attention (2 q-frags/wave + K/V dbuf) --------
// NO-MAX softmax (bounded S after RMSNorm), P = exp2(S) directly.
__global__ __launch_bounds__(256, 2) void attn_fwd(const u16* __restrict__ Q,
                                                   const u16* __restrict__ Kg,
                                                   const u16* __restrict__ Vg,
                                                   u16* __restrict__ AO) {
  __shared__ __attribute__((aligned(16))) u16 Ks[2][64 * 128];
  __shared__ __attribute__((aligned(16))) u16 Vt[2][128 * 64];
  __shared__ __attribute__((aligned(16))) u16 Plds[4][32 * 64];
  const int tid = threadIdx.x;
  const int lane = tid & 63;
  const int w = tid >> 6;
  const int r = lane & 15, g = lane >> 4;
  const int p = blockIdx.x, h = blockIdx.y, b = blockIdx.z;
  const int hkv = h >> 2;

  const u16* Kp = Kg + (((size_t)b * 8 + hkv) * 2048) * 128;
  const u16* Vp = Vg + (((size_t)b * 8 + hkv) * 128) * 2048;

  const short one_bf = (short)0x3F80;
  const bf16x8 vones = {one_bf, one_bf, one_bf, one_bf, one_bf, one_bf, one_bf, one_bf};

#pragma unroll 1
  for (int phase = 0; phase < 2; ++phase) {
    const int qt = phase == 0 ? (15 - p) : p;
    const u16* Qp = Q + (((size_t)b * 32 + h) * 2048 + qt * 128 + w * 32) * 128;

    bf16x8 qf[2][4];
#pragma unroll
    for (int f = 0; f < 2; ++f)
#pragma unroll
      for (int kk = 0; kk < 4; ++kk)
        qf[f][kk] = *(const bf16x8*)(Qp + (f * 16 + r) * 128 + kk * 32 + g * 8);

    f32x4 off[2][8];
#pragma unroll
    for (int f = 0; f < 2; ++f)
#pragma unroll
      for (int i = 0; i < 8; ++i) off[f][i] = (f32x4){0.f, 0.f, 0.f, 0.f};
    f32x4 lr4[2] = {(f32x4){0.f, 0.f, 0.f, 0.f}, (f32x4){0.f, 0.f, 0.f, 0.f}};
    const int qg0 = qt * 128 + w * 32 + r;
    const int qg1 = qg0 + 16;

    const u16* kst[4];
    const u16* vst[4];
#pragma unroll
    for (int c = 0; c < 4; ++c) {
      int t = c * 256 + tid;
      kst[c] = Kp + (size_t)(t >> 4) * 128 + (size_t)(((t & 15) ^ ((t >> 4) & 7)) * 8);
      int d = t >> 3;
      vst[c] = Vp + (size_t)d * 2048 + (size_t)(((t & 7) ^ ((d >> 1) & 7)) * 8);
    }
    auto stageKV = [&](int buf) {
#pragma unroll
      for (int c = 0; c < 4; ++c) {
        gload16(kst[c], (char*)&Ks[buf][0] + c * 4096 + w * 1024);
        kst[c] += 64 * 128;
      }
#pragma unroll
      for (int c = 0; c < 4; ++c) {
        gload16(vst[c], (char*)&Vt[buf][0] + c * 4096 + w * 1024);
        vst[c] += 64;
      }
    };

    const int nu = 2 * qt + 2;

    stageKV(0);
    WAITV(0);
    BAR();

    for (int kt = 0; kt < nu; ++kt) {
      const int cur = kt & 1;
      if (kt + 1 < nu) stageKV(cur ^ 1);

      const char* KsC = (const char*)&Ks[cur][0];
      const char* VtC = (const char*)&Vt[cur][0];

      f32x4 sc0[4], sc1[4];
#pragma unroll
      for (int ni = 0; ni < 4; ++ni) {
        f32x4 a0 = (f32x4){0.f, 0.f, 0.f, 0.f};
        f32x4 a1 = (f32x4){0.f, 0.f, 0.f, 0.f};
        int ro = ni * 16 + r;
#pragma unroll
        for (int kk = 0; kk < 4; ++kk) {
          int slot = (ro * 16 + kk * 4 + g) ^ (ro & 7);
          bf16x8 kf = *(const bf16x8*)(KsC + slot * 16);
          a0 = MFMA(kf, qf[0][kk], a0, 0, 0, 0);
          a1 = MFMA(kf, qf[1][kk], a1, 0, 0, 0);
        }
        sc0[ni] = a0;
        sc1[ni] = a1;
      }

      if (kt >= 2 * qt) {
#pragma unroll
        for (int ni = 0; ni < 4; ++ni)
#pragma unroll
          for (int j = 0; j < 4; ++j) {
            int kvg = kt * 64 + ni * 16 + g * 4 + j;
            sc0[ni][j] = (kvg > qg0) ? -1e30f : sc0[ni][j];
            sc1[ni][j] = (kvg > qg1) ? -1e30f : sc1[ni][j];
          }
      }

      {
        char* pw = (char*)&Plds[w][0];
        int sw = (r & 7) << 4;
#pragma unroll
        for (int ni = 0; ni < 4; ++ni) {
          u32x2 pr0, pr1;
          pr0[0] = cvtpk(exp2f(sc0[ni][0]), exp2f(sc0[ni][1]));
          pr0[1] = cvtpk(exp2f(sc0[ni][2]), exp2f(sc0[ni][3]));
          pr1[0] = cvtpk(exp2f(sc1[ni][0]), exp2f(sc1[ni][1]));
          pr1[1] = cvtpk(exp2f(sc1[ni][2]), exp2f(sc1[ni][3]));
          *(u32x2*)(pw + ((r * 128 + ni * 32 + g * 8) ^ sw)) = pr0;
          *(u32x2*)(pw + (((16 + r) * 128 + ni * 32 + g * 8) ^ sw)) = pr1;
        }
      }
      bf16x8 pa[2][2];
      {
        const char* pw = (const char*)&Plds[w][0];
        int sw = (r & 7) << 4;
#pragma unroll
        for (int kk = 0; kk < 2; ++kk) {
          pa[0][kk] = *(const bf16x8*)(pw + ((r * 128 + kk * 64 + g * 16) ^ sw));
          pa[1][kk] = *(const bf16x8*)(pw + (((16 + r) * 128 + kk * 64 + g * 16) ^ sw));
        }
      }

      lr4[0] = MFMA(pa[0][0], vones, lr4[0], 0, 0, 0);
      lr4[0] = MFMA(pa[0][1], vones, lr4[0], 0, 0, 0);
      lr4[1] = MFMA(pa[1][0], vones, lr4[1], 0, 0, 0);
      lr4[1] = MFMA(pa[1][1], vones, lr4[1], 0, 0, 0);

#pragma unroll
      for (int dd = 0; dd < 8; ++dd) {
        int d = dd * 16 + r;
#pragma unroll
        for (int kk = 0; kk < 2; ++kk) {
          int ph = (kk * 4 + g) ^ ((r >> 1) & 7);
          bf16x8 vf = *(const bf16x8*)(VtC + (size_t)d * 128 + ph * 16);
          off[0][dd] = MFMA(pa[0][kk], vf, off[0][dd], 0, 0, 0);
          off[1][dd] = MFMA(pa[1][kk], vf, off[1][dd], 0, 0, 0);
        }
      }

      WAITV(0);
      BAR();
    }

#pragma unroll
    for (int f = 0; f < 2; ++f) {
      f32x4 il4;
#pragma unroll
      for (int j = 0; j < 4; ++j) il4[j] = 1.0f / lr4[f][j];
      const size_t ob = (size_t)b * 2048 + qt * 128 + w * 32 + f * 16 + g * 4;
#pragma unroll
      for (int dd = 0; dd < 8; ++dd) {
        AO[(ob + 0) * 4096 + h * 128 + dd * 16 + r] = f2b(off[f][dd][0] * il4[0]);
        AO[(ob + 1) * 4096 + h * 128 + dd * 16 + r] = f2b(off[f][dd][1] * il4[1]);
        AO[(ob + 2) * 4096 + h * 128 + dd * 16 + r] = f2b(off[f][dd][2] * il4[2]);
        AO[(ob + 3) * 4096 + h * 128 + dd * 16 + r] = f2b(off[f][dd][3] * il4[3]);
      }
    }
  }
}

// ---------------- launch ----------------
extern "C" void kernel_launch(void* const* d_in, const int* in_sizes, int n_in,
                              void* d_out, int out_size, void* d_ws, size_t ws_size,
                              hipStream_t stream) {
  (void)in_sizes; (void)n_in; (void)out_size; (void)ws_size;
  const float* hs = (const float*)d_in[0];
  const float* cosT = (const float*)d_in[1];
  const float* sinT = (const float*)d_in[2];
  const float* wq = (const float*)d_in[3];
  const float* wk = (const float*)d_in[4];
  const float* wv = (const float*)d_in[5];
  const float* wo = (const float*)d_in[6];
  const float* qnw = (const float*)d_in[7];
  const float* knw = (const float*)d_in[8];
  float* out = (float*)d_out;

  char* ws = (char*)d_ws;
  u16* hsb  = (u16*)(ws);                   // [4096,2048]      16 MB
  u16* wqkv = (u16*)(ws + 16777216);        // [6144,2048]      24 MB
  u16* wob  = (u16*)(ws + 41943040);        // [2048,4096]      16 MB
  u16* Qb   = (u16*)(ws + 58720256);        // [2,32,2048,128]  32 MB
  u16* Kb   = (u16*)(ws + 92274688);        // [2,8,2048,128]    8 MB
  u16* VTb  = (u16*)(ws + 100663296);       // [2,8,128,2048]    8 MB (transposed)
  u16* AO   = (u16*)(ws + 109051904);       // [4096,4096]      32 MB
  float* P0 = (float*)(ws + 58720256);      // 32 MB, aliases Qb (dead after attn)
  float* P1 = (float*)(ws);                 // 32 MB, aliases hsb+wqkv

  // 1) fp32 -> bf16 (all tensors, one launch)
  cvt_all<<<14336, 256, 0, stream>>>(hs, wq, wk, wv, wo, hsb, wqkv, wob);

  // 2) fused QKV projection + RMSNorm + RoPE + V-transpose (2D XCD regions)
  gemm256<0><<<384, 512, 0, stream>>>(hsb, wqkv, Qb, Kb, VTb, nullptr, nullptr,
                                      cosT, sinT, qnw, knw, 2048, 2048, 24, 384);

  // 3) causal GQA flash attention (QBLK=128, paired {15-p,p}) -> AO bf16
  attn_fwd<<<dim3(8, 32, 2), 256, 0, stream>>>(Qb, Kb, VTb, AO);

  // 4) output projection: split-K=2 plain-store partials, then reduce
  gemm256<1><<<256, 512, 0, stream>>>(AO, wob, nullptr, nullptr, nullptr, P0, P1,
                                      nullptr, nullptr, nullptr, nullptr,
                                      4096, 2048, 8, 256);
  reduce_add<<<8192, 256, 0, stream>>>(P0, P1, out, 2097152);
}